// Round 5
// baseline (514.771 us; speedup 1.0000x reference)
//
#include <hip/hip_runtime.h>

#define NN 50000
#define NE 800000
#define NB 128
#define FIN 30
#define H 64
#define NC 10
#define L 3
#define TILE 32

typedef unsigned int uint;
typedef unsigned short ushort;

// f32 -> bf16 round-to-nearest-even (finite inputs)
__device__ __forceinline__ ushort f2bf(float x) {
    uint u = __float_as_uint(x);
    u += 0x7fffu + ((u >> 16) & 1u);
    return (ushort)(u >> 16);
}
__device__ __forceinline__ float bf_lo(uint v) { return __uint_as_float(v << 16); }
__device__ __forceinline__ float bf_hi(uint v) { return __uint_as_float(v & 0xffff0000u); }

// ---------------- kernels ----------------

// h0 = concat(x, emb_port[ports], emb_flags[flags]) in bf16; also zeroes cnt.
// thread = (node n, feature-pair fp); 32 threads/node.
__global__ __launch_bounds__(256) void embed_concat_kernel(
    const float* __restrict__ x, const int* __restrict__ ports,
    const int* __restrict__ flags, const float* __restrict__ emb_port,
    const float* __restrict__ emb_flags, ushort* __restrict__ h,
    int* __restrict__ cnt)
{
    int tid = blockIdx.x * 256 + threadIdx.x;
    int n = tid >> 5, fp = tid & 31;
    if (n >= NN) return;
    if (fp == 0) cnt[n] = 0;
    int f0 = fp * 2;
    float v0, v1;
    if (f0 < FIN) {
        float2 xv = *(const float2*)(x + (size_t)n * FIN + f0);
        v0 = xv.x; v1 = xv.y;
    } else if (f0 < FIN + 32) {
        float2 pv = *(const float2*)(emb_port + (size_t)ports[n] * 32 + (f0 - FIN));
        v0 = pv.x; v1 = pv.y;
    } else {
        float2 fv = *(const float2*)(emb_flags + (size_t)flags[n] * 2);
        v0 = fv.x; v1 = fv.y;
    }
    uint o = (uint)f2bf(v0) | ((uint)f2bf(v1) << 16);
    ((uint*)h)[n * 32 + fp] = o;
}

__global__ __launch_bounds__(256) void hist_kernel(
    const int* __restrict__ dst, int* __restrict__ cnt)
{
    int e = blockIdx.x * 256 + threadIdx.x;
    if (e < NE) atomicAdd(&cnt[dst[e]], 1);
}

// ---- hierarchical scan; also zeroes cursor (used later by scatter) ----

__global__ __launch_bounds__(1024) void scan1_kernel(
    const int* __restrict__ cnt, int* __restrict__ row_start,
    int* __restrict__ bsum, int* __restrict__ cursor)
{
    __shared__ int wsum[16];
    int i = blockIdx.x * 1024 + threadIdx.x;
    int lane = threadIdx.x & 63;
    int wv = threadIdx.x >> 6;
    if (i < NN) cursor[i] = 0;
    int v = (i < NN) ? cnt[i] : 0;
    int s = v;
    for (int off = 1; off < 64; off <<= 1) {
        int t = __shfl_up(s, off);
        if (lane >= off) s += t;
    }
    if (lane == 63) wsum[wv] = s;
    __syncthreads();
    if (wv == 0) {
        int ws = (lane < 16) ? wsum[lane] : 0;
        for (int off = 1; off < 16; off <<= 1) {
            int t = __shfl_up(ws, off);
            if (lane >= off) ws += t;
        }
        if (lane < 16) wsum[lane] = ws;
    }
    __syncthreads();
    int base = (wv > 0) ? wsum[wv - 1] : 0;
    s += base;
    if (i < NN) row_start[i + 1] = s;
    if (threadIdx.x == 1023) bsum[blockIdx.x] = s;
    if (i == 0) row_start[0] = 0;
}

__global__ __launch_bounds__(64) void scan2_kernel(int* __restrict__ bsum)
{
    int lane = threadIdx.x;
    int v = (lane < 49) ? bsum[lane] : 0;
    for (int off = 1; off < 64; off <<= 1) {
        int t = __shfl_up(v, off);
        if (lane >= off) v += t;
    }
    if (lane < 49) bsum[lane] = v;
}

__global__ __launch_bounds__(1024) void scan3_kernel(
    int* __restrict__ row_start, const int* __restrict__ bsum)
{
    int b = blockIdx.x + 1;
    int i = b * 1024 + threadIdx.x;
    if (i < NN) row_start[i + 1] += bsum[b - 1];
}

// CSR bucket fill; stores BYTE offsets (src * 128) for direct gather addressing
__global__ __launch_bounds__(256) void scatter_edges_kernel(
    const int* __restrict__ src, const int* __restrict__ dst,
    const int* __restrict__ row_start, int* __restrict__ cursor,
    int* __restrict__ edge_src)
{
    int e = blockIdx.x * 256 + threadIdx.x;
    if (e >= NE) return;
    int d = dst[e];
    int pos = atomicAdd(&cursor[d], 1);
    edge_src[row_start[d] + pos] = src[e] << 7;
}

// fused GraphConv layer, bf16 h: gather-sum + (agg@Wrel^T + brel + h@Wroot^T) + relu
// TILE=32 nodes/block, 4 waves; gather lane = (edge-slot sub 0..7, feature-octet f8);
// 8 edges per wave-load, 2 predicated batches in flight (16 edges).
__global__ __launch_bounds__(256, 6) void conv_kernel(
    const ushort* __restrict__ h_in, ushort* __restrict__ h_out,
    const int* __restrict__ row_start, const int* __restrict__ edge_src,
    const float* __restrict__ Wrel, const float* __restrict__ brel,
    const float* __restrict__ Wroot)
{
    __shared__ float sa[TILE * 65];   // aggregated neighbor sums (f32)
    __shared__ float sh[TILE * 65];   // self rows (f32, from bf16)
    __shared__ int rs[TILE + 1];
    int node0 = blockIdx.x * TILE;
    int tid = threadIdx.x;
    int lane = tid & 63;
    int w = tid >> 6;
    int f8 = lane & 7;       // feature octet (8 features per lane)
    int sub = lane >> 3;     // edge slot 0..7

    if (tid < TILE + 1) {
        int idx = node0 + tid; if (idx > NN) idx = NN;
        rs[tid] = row_start[idx];
    }
    // self staging: 256 threads x 16B (8 bf16 -> f32)
    {
        int r = tid >> 3, oct = tid & 7;
        uint4 v = make_uint4(0u, 0u, 0u, 0u);
        if (node0 + r < NN)
            v = *((const uint4*)(h_in + (size_t)node0 * H) + tid);
        float* d = &sh[r * 65 + oct * 8];
        d[0] = bf_lo(v.x); d[1] = bf_hi(v.x);
        d[2] = bf_lo(v.y); d[3] = bf_hi(v.y);
        d[4] = bf_lo(v.z); d[5] = bf_hi(v.z);
        d[6] = bf_lo(v.w); d[7] = bf_hi(v.w);
    }
    __syncthreads();

    const char* hb = (const char*)h_in;
    // gather: wave w handles rows w*8 .. w*8+7
    for (int i = 0; i < 8; ++i) {
        int r = w * 8 + i;
        int p1 = rs[r + 1];
        int p  = rs[r] + sub;
        float a[8] = {0.f,0.f,0.f,0.f,0.f,0.f,0.f,0.f};
        float b[8] = {0.f,0.f,0.f,0.f,0.f,0.f,0.f,0.f};
        while (p < p1) {
            int off0 = edge_src[p];
            bool g1 = (p + 8) < p1;
            int off1 = g1 ? edge_src[p + 8] : 0;
            uint4 v0 = *(const uint4*)(hb + off0 + f8 * 16);
            uint4 v1 = make_uint4(0u, 0u, 0u, 0u);
            if (g1) v1 = *(const uint4*)(hb + off1 + f8 * 16);
            a[0] += bf_lo(v0.x); a[1] += bf_hi(v0.x);
            a[2] += bf_lo(v0.y); a[3] += bf_hi(v0.y);
            a[4] += bf_lo(v0.z); a[5] += bf_hi(v0.z);
            a[6] += bf_lo(v0.w); a[7] += bf_hi(v0.w);
            b[0] += bf_lo(v1.x); b[1] += bf_hi(v1.x);
            b[2] += bf_lo(v1.y); b[3] += bf_hi(v1.y);
            b[4] += bf_lo(v1.z); b[5] += bf_hi(v1.z);
            b[6] += bf_lo(v1.w); b[7] += bf_hi(v1.w);
            p += 16;
        }
#pragma unroll
        for (int e = 0; e < 8; ++e) a[e] += b[e];
        // butterfly over the 8 edge slots (lane bits 3,4,5)
#pragma unroll
        for (int m = 8; m <= 32; m <<= 1) {
#pragma unroll
            for (int e = 0; e < 8; ++e) a[e] += __shfl_xor(a[e], m);
        }
        if (sub == 0) {
            float* d = &sa[r * 65 + f8 * 8];
#pragma unroll
            for (int e = 0; e < 8; ++e) d[e] = a[e];
        }
    }
    __syncthreads();

    // linear phase: thread = (node r2, 8-feature chunk c)
    int r2 = tid & 31;
    int c  = tid >> 5;
    int jt = c * 8;
    int n2 = node0 + r2;
    float acc[8];
#pragma unroll
    for (int j = 0; j < 8; ++j) acc[j] = brel[jt + j];
#pragma unroll 4
    for (int k = 0; k < 64; ++k) {
        float av = sa[r2 * 65 + k];
        float hv = sh[r2 * 65 + k];
#pragma unroll
        for (int j = 0; j < 8; ++j) {
            acc[j] = fmaf(av, Wrel[(jt + j) * 64 + k],
                     fmaf(hv, Wroot[(jt + j) * 64 + k], acc[j]));
        }
    }
    if (n2 < NN) {
        uint o[4];
#pragma unroll
        for (int q = 0; q < 4; ++q) {
            float lo = fmaxf(acc[2 * q],     0.f);
            float hi = fmaxf(acc[2 * q + 1], 0.f);
            o[q] = (uint)f2bf(lo) | ((uint)f2bf(hi) << 16);
        }
        *(uint4*)(h_out + (size_t)n2 * H + jt) = make_uint4(o[0], o[1], o[2], o[3]);
    }
}

// block-per-graph max pool: binary search node range on sorted batch; no atomics
__global__ __launch_bounds__(256) void pool_max_kernel(
    const ushort* __restrict__ h, const int* __restrict__ batch,
    float* __restrict__ g)
{
    __shared__ float red[4][64];
    int b = blockIdx.x;
    int tid = threadIdx.x;
    int f = tid & 63, w = tid >> 6;
    // lower_bound(batch, b) and lower_bound(batch, b+1)
    int lo = 0, hi = NN;
    while (lo < hi) { int mid = (lo + hi) >> 1; if (batch[mid] < b) lo = mid + 1; else hi = mid; }
    int lo2 = lo, hi2 = NN;
    while (lo2 < hi2) { int mid = (lo2 + hi2) >> 1; if (batch[mid] < b + 1) lo2 = mid + 1; else hi2 = mid; }
    float m = -3.402823466e38f;
    for (int n = lo + w; n < lo2; n += 4) {
        ushort u = h[(size_t)n * H + f];
        m = fmaxf(m, __uint_as_float((uint)u << 16));
    }
    red[w][f] = m;
    __syncthreads();
    if (tid < 64) {
        float mm = fmaxf(fmaxf(red[0][f], red[1][f]), fmaxf(red[2][f], red[3][f]));
        g[b * H + f] = mm;
    }
}

__global__ __launch_bounds__(64) void mlp_kernel(
    const float* __restrict__ g,
    const float* __restrict__ fc1W, const float* __restrict__ fc1b,
    const float* __restrict__ fc2W, const float* __restrict__ fc2b,
    const float* __restrict__ fc3W, const float* __restrict__ fc3b,
    float* __restrict__ out)
{
    __shared__ float s0[64];
    __shared__ float s1[64];
    int b = blockIdx.x, j = threadIdx.x;
    s0[j] = g[b * H + j];
    __syncthreads();
    float acc = fc1b[j];
    for (int k = 0; k < 64; ++k) acc = fmaf(s0[k], fc1W[j * 64 + k], acc);
    s1[j] = fmaxf(acc, 0.f);
    __syncthreads();
    acc = fc2b[j];
    for (int k = 0; k < 64; ++k) acc = fmaf(s1[k], fc2W[j * 64 + k], acc);
    __syncthreads();
    s0[j] = fmaxf(acc, 0.f);
    __syncthreads();
    if (j < NC) {
        acc = fc3b[j];
        for (int k = 0; k < 64; ++k) acc = fmaf(s0[k], fc3W[j * 64 + k], acc);
        out[b * NC + j] = acc;
    }
}

// ---------------- launcher ----------------

extern "C" void kernel_launch(void* const* d_in, const int* in_sizes, int n_in,
                              void* d_out, int out_size, void* d_ws, size_t ws_size,
                              hipStream_t stream)
{
    const float* x         = (const float*)d_in[0];
    const int*   dst_ports = (const int*)d_in[1];
    const int*   tcp_flags = (const int*)d_in[2];
    const int*   edge_src_in = (const int*)d_in[3];          // row 0 of (2,E)
    const int*   edge_dst_in = edge_src_in + NE;             // row 1
    const int*   batch     = (const int*)d_in[4];
    const float* emb_port  = (const float*)d_in[5];
    const float* emb_flags = (const float*)d_in[6];
    const float* Wrel      = (const float*)d_in[7];
    const float* brel      = (const float*)d_in[8];
    const float* Wroot     = (const float*)d_in[9];
    const float* fc1W      = (const float*)d_in[10];
    const float* fc1b      = (const float*)d_in[11];
    const float* fc2W      = (const float*)d_in[12];
    const float* fc2b      = (const float*)d_in[13];
    const float* fc3W      = (const float*)d_in[14];
    const float* fc3b      = (const float*)d_in[15];
    float* out = (float*)d_out;

    // workspace carve-up (256B aligned)
    char* ws = (char*)d_ws;
    size_t off = 0;
    auto alloc = [&](size_t bytes) {
        void* p = ws + off;
        off += (bytes + 255) & ~(size_t)255;
        return p;
    };
    ushort* h0      = (ushort*)alloc((size_t)NN * H * 2);
    ushort* h1      = (ushort*)alloc((size_t)NN * H * 2);
    int*   cnt      = (int*)alloc((size_t)NN * 4);
    int*   row_start= (int*)alloc((size_t)(NN + 1) * 4);
    int*   cursor   = (int*)alloc((size_t)NN * 4);
    int*   edge_src = (int*)alloc((size_t)NE * 4);
    float* g        = (float*)alloc((size_t)NB * H * 4);
    int*   bsum     = (int*)alloc((size_t)64 * 4);

    // h0 = concat(...) in bf16; also zeroes cnt (before hist)
    embed_concat_kernel<<<(NN * 32 + 255) / 256, 256, 0, stream>>>(
        x, dst_ports, tcp_flags, emb_port, emb_flags, h0, cnt);

    // CSR build (by dst)
    hist_kernel<<<(NE + 255) / 256, 256, 0, stream>>>(edge_dst_in, cnt);
    scan1_kernel<<<(NN + 1023) / 1024, 1024, 0, stream>>>(cnt, row_start, bsum, cursor);
    scan2_kernel<<<1, 64, 0, stream>>>(bsum);
    scan3_kernel<<<(NN + 1023) / 1024 - 1, 1024, 0, stream>>>(row_start, bsum);
    scatter_edges_kernel<<<(NE + 255) / 256, 256, 0, stream>>>(
        edge_src_in, edge_dst_in, row_start, cursor, edge_src);

    // 3 fused GraphConv layers, ping-pong
    const int cgrid = (NN + TILE - 1) / TILE;
    conv_kernel<<<cgrid, 256, 0, stream>>>(
        h0, h1, row_start, edge_src, Wrel + 0 * H * H, brel + 0 * H, Wroot + 0 * H * H);
    conv_kernel<<<cgrid, 256, 0, stream>>>(
        h1, h0, row_start, edge_src, Wrel + 1 * H * H, brel + 1 * H, Wroot + 1 * H * H);
    conv_kernel<<<cgrid, 256, 0, stream>>>(
        h0, h1, row_start, edge_src, Wrel + 2 * H * H, brel + 2 * H, Wroot + 2 * H * H);

    // global max pool (final h is h1), block per graph, no atomics
    pool_max_kernel<<<NB, 256, 0, stream>>>(h1, batch, g);

    // MLP head
    mlp_kernel<<<NB, 64, 0, stream>>>(g, fc1W, fc1b, fc2W, fc2b, fc3W, fc3b, out);
}

// Round 6
// 442.917 us; speedup vs baseline: 1.1622x; 1.1622x over previous
//
#include <hip/hip_runtime.h>

#define NN 50000
#define NE 800000
#define NB 128
#define FIN 30
#define H 64
#define NC 10
#define L 3
#define TILE 32

typedef unsigned int uint;
typedef unsigned short ushort;

// f32 -> bf16 round-to-nearest-even (finite inputs)
__device__ __forceinline__ ushort f2bf(float x) {
    uint u = __float_as_uint(x);
    u += 0x7fffu + ((u >> 16) & 1u);
    return (ushort)(u >> 16);
}
__device__ __forceinline__ float bf_lo(uint v) { return __uint_as_float(v << 16); }
__device__ __forceinline__ float bf_hi(uint v) { return __uint_as_float(v & 0xffff0000u); }

// ---------------- kernels ----------------

// h0 = concat(x, emb_port[ports], emb_flags[flags]) in bf16; also zeroes cnt.
__global__ __launch_bounds__(256) void embed_concat_kernel(
    const float* __restrict__ x, const int* __restrict__ ports,
    const int* __restrict__ flags, const float* __restrict__ emb_port,
    const float* __restrict__ emb_flags, ushort* __restrict__ h,
    int* __restrict__ cnt)
{
    int tid = blockIdx.x * 256 + threadIdx.x;
    int n = tid >> 5, fp = tid & 31;
    if (n >= NN) return;
    if (fp == 0) cnt[n] = 0;
    int f0 = fp * 2;
    float v0, v1;
    if (f0 < FIN) {
        float2 xv = *(const float2*)(x + (size_t)n * FIN + f0);
        v0 = xv.x; v1 = xv.y;
    } else if (f0 < FIN + 32) {
        float2 pv = *(const float2*)(emb_port + (size_t)ports[n] * 32 + (f0 - FIN));
        v0 = pv.x; v1 = pv.y;
    } else {
        float2 fv = *(const float2*)(emb_flags + (size_t)flags[n] * 2);
        v0 = fv.x; v1 = fv.y;
    }
    uint o = (uint)f2bf(v0) | ((uint)f2bf(v1) << 16);
    ((uint*)h)[n * 32 + fp] = o;
}

__global__ __launch_bounds__(256) void hist_kernel(
    const int* __restrict__ dst, int* __restrict__ cnt)
{
    int e = blockIdx.x * 256 + threadIdx.x;
    if (e < NE) atomicAdd(&cnt[dst[e]], 1);
}

// ---- hierarchical scan; also zeroes cursor (used later by scatter) ----

__global__ __launch_bounds__(1024) void scan1_kernel(
    const int* __restrict__ cnt, int* __restrict__ row_start,
    int* __restrict__ bsum, int* __restrict__ cursor)
{
    __shared__ int wsum[16];
    int i = blockIdx.x * 1024 + threadIdx.x;
    int lane = threadIdx.x & 63;
    int wv = threadIdx.x >> 6;
    if (i < NN) cursor[i] = 0;
    int v = (i < NN) ? cnt[i] : 0;
    int s = v;
    for (int off = 1; off < 64; off <<= 1) {
        int t = __shfl_up(s, off);
        if (lane >= off) s += t;
    }
    if (lane == 63) wsum[wv] = s;
    __syncthreads();
    if (wv == 0) {
        int ws = (lane < 16) ? wsum[lane] : 0;
        for (int off = 1; off < 16; off <<= 1) {
            int t = __shfl_up(ws, off);
            if (lane >= off) ws += t;
        }
        if (lane < 16) wsum[lane] = ws;
    }
    __syncthreads();
    int base = (wv > 0) ? wsum[wv - 1] : 0;
    s += base;
    if (i < NN) row_start[i + 1] = s;
    if (threadIdx.x == 1023) bsum[blockIdx.x] = s;
    if (i == 0) row_start[0] = 0;
}

__global__ __launch_bounds__(64) void scan2_kernel(int* __restrict__ bsum)
{
    int lane = threadIdx.x;
    int v = (lane < 49) ? bsum[lane] : 0;
    for (int off = 1; off < 64; off <<= 1) {
        int t = __shfl_up(v, off);
        if (lane >= off) v += t;
    }
    if (lane < 49) bsum[lane] = v;
}

__global__ __launch_bounds__(1024) void scan3_kernel(
    int* __restrict__ row_start, const int* __restrict__ bsum)
{
    int b = blockIdx.x + 1;
    int i = b * 1024 + threadIdx.x;
    if (i < NN) row_start[i + 1] += bsum[b - 1];
}

// CSR bucket fill; stores BYTE offsets (src * 128) for direct gather addressing.
// Index guard keeps rocprof counter-replay (which re-runs this dispatch without
// re-zeroing cursor) from writing out of bounds.
__global__ __launch_bounds__(256) void scatter_edges_kernel(
    const int* __restrict__ src, const int* __restrict__ dst,
    const int* __restrict__ row_start, int* __restrict__ cursor,
    int* __restrict__ edge_src)
{
    int e = blockIdx.x * 256 + threadIdx.x;
    if (e >= NE) return;
    int d = dst[e];
    int pos = atomicAdd(&cursor[d], 1);
    int idx = row_start[d] + pos;
    if (idx < NE) edge_src[idx] = src[e] << 7;
}

// fused GraphConv layer, bf16 h: gather-sum + (agg@Wrel^T + brel + h@Wroot^T) + relu
// TILE=32 nodes/block, 4 waves; gather lane = (edge-slot sub 0..7, feature-octet f8);
// 4 predicated batches -> 32 edges in flight per row. Output restaged through LDS
// so the global store pass is tid-linear (full 64B lines per wave instruction).
__global__ __launch_bounds__(256) void conv_kernel(
    const ushort* __restrict__ h_in, ushort* __restrict__ h_out,
    const int* __restrict__ row_start, const int* __restrict__ edge_src,
    const float* __restrict__ Wrel, const float* __restrict__ brel,
    const float* __restrict__ Wroot)
{
    __shared__ float sa[TILE * 65];   // aggregated neighbor sums (f32); reused as out-stage
    __shared__ float sh[TILE * 65];   // self rows (f32, from bf16)
    __shared__ int rs[TILE + 1];
    int node0 = blockIdx.x * TILE;
    int tid = threadIdx.x;
    int lane = tid & 63;
    int w = tid >> 6;
    int f8 = lane & 7;       // feature octet (8 features per lane)
    int sub = lane >> 3;     // edge slot 0..7

    if (tid < TILE + 1) {
        int idx = node0 + tid; if (idx > NN) idx = NN;
        rs[tid] = row_start[idx];
    }
    // self staging: 256 threads x 16B (8 bf16 -> f32)
    {
        int r = tid >> 3, oct = tid & 7;
        uint4 v = make_uint4(0u, 0u, 0u, 0u);
        if (node0 + r < NN)
            v = *((const uint4*)(h_in + (size_t)node0 * H) + tid);
        float* d = &sh[r * 65 + oct * 8];
        d[0] = bf_lo(v.x); d[1] = bf_hi(v.x);
        d[2] = bf_lo(v.y); d[3] = bf_hi(v.y);
        d[4] = bf_lo(v.z); d[5] = bf_hi(v.z);
        d[6] = bf_lo(v.w); d[7] = bf_hi(v.w);
    }
    __syncthreads();

    const char* hb = (const char*)h_in;
    // gather: wave w handles rows w*8 .. w*8+7; 4 batches of 8 edges in flight
    for (int i = 0; i < 8; ++i) {
        int r = w * 8 + i;
        int p1 = rs[r + 1];
        int p0 = rs[r];
        float a[8] = {0.f,0.f,0.f,0.f,0.f,0.f,0.f,0.f};
        for (int p = p0 + sub; p < p1; p += 32) {
            bool g1 = (p + 8)  < p1;
            bool g2 = (p + 16) < p1;
            bool g3 = (p + 24) < p1;
            int o0 = edge_src[p];
            int o1 = 0, o2 = 0, o3 = 0;
            if (g1) o1 = edge_src[p + 8];
            if (g2) o2 = edge_src[p + 16];
            if (g3) o3 = edge_src[p + 24];
            uint4 v0 = *(const uint4*)(hb + o0 + f8 * 16);
            uint4 v1 = make_uint4(0u,0u,0u,0u);
            uint4 v2 = make_uint4(0u,0u,0u,0u);
            uint4 v3 = make_uint4(0u,0u,0u,0u);
            if (g1) v1 = *(const uint4*)(hb + o1 + f8 * 16);
            if (g2) v2 = *(const uint4*)(hb + o2 + f8 * 16);
            if (g3) v3 = *(const uint4*)(hb + o3 + f8 * 16);
            a[0] += (bf_lo(v0.x) + bf_lo(v1.x)) + (bf_lo(v2.x) + bf_lo(v3.x));
            a[1] += (bf_hi(v0.x) + bf_hi(v1.x)) + (bf_hi(v2.x) + bf_hi(v3.x));
            a[2] += (bf_lo(v0.y) + bf_lo(v1.y)) + (bf_lo(v2.y) + bf_lo(v3.y));
            a[3] += (bf_hi(v0.y) + bf_hi(v1.y)) + (bf_hi(v2.y) + bf_hi(v3.y));
            a[4] += (bf_lo(v0.z) + bf_lo(v1.z)) + (bf_lo(v2.z) + bf_lo(v3.z));
            a[5] += (bf_hi(v0.z) + bf_hi(v1.z)) + (bf_hi(v2.z) + bf_hi(v3.z));
            a[6] += (bf_lo(v0.w) + bf_lo(v1.w)) + (bf_lo(v2.w) + bf_lo(v3.w));
            a[7] += (bf_hi(v0.w) + bf_hi(v1.w)) + (bf_hi(v2.w) + bf_hi(v3.w));
        }
        // butterfly over the 8 edge slots (lane bits 3,4,5)
#pragma unroll
        for (int m = 8; m <= 32; m <<= 1) {
#pragma unroll
            for (int e = 0; e < 8; ++e) a[e] += __shfl_xor(a[e], m);
        }
        if (sub == 0) {
            float* d = &sa[r * 65 + f8 * 8];
#pragma unroll
            for (int e = 0; e < 8; ++e) d[e] = a[e];
        }
    }
    __syncthreads();

    // linear phase: thread = (node r2, 8-feature chunk c); weights via scalar path
    int r2 = tid & 31;
    int c  = tid >> 5;
    int jt = __builtin_amdgcn_readfirstlane(c * 8);  // wave-uniform (c = 2w or 2w+1... per 32-lane half)
    // NOTE: c = tid>>5 is uniform per 32-lane half, not per wave; use plain c*8 to be safe:
    jt = c * 8;
    float acc[8];
#pragma unroll
    for (int j = 0; j < 8; ++j) acc[j] = brel[jt + j];
#pragma unroll 4
    for (int k = 0; k < 64; ++k) {
        float av = sa[r2 * 65 + k];
        float hv = sh[r2 * 65 + k];
#pragma unroll
        for (int j = 0; j < 8; ++j) {
            acc[j] = fmaf(av, Wrel[(jt + j) * 64 + k],
                     fmaf(hv, Wroot[(jt + j) * 64 + k], acc[j]));
        }
    }
    __syncthreads();   // all sa/sh reads done; safe to reuse sa as output stage

    // pack relu(acc) as bf16 pairs into padded LDS stage: [32 rows][33 words]
    {
        uint* sa_u = (uint*)sa;
#pragma unroll
        for (int q = 0; q < 4; ++q) {
            float lo = fmaxf(acc[2 * q],     0.f);
            float hi = fmaxf(acc[2 * q + 1], 0.f);
            sa_u[r2 * 33 + c * 4 + q] = (uint)f2bf(lo) | ((uint)f2bf(hi) << 16);
        }
    }
    __syncthreads();

    // coalesced store pass: thread tid writes 16B at byte offset tid*16 of the tile
    {
        const uint* sa_u = (const uint*)sa;
        int row = tid >> 3;              // 8 threads per 128B row
        int o   = tid & 7;
        if (node0 + row < NN) {
            uint4 v;
            v.x = sa_u[row * 33 + o * 4 + 0];
            v.y = sa_u[row * 33 + o * 4 + 1];
            v.z = sa_u[row * 33 + o * 4 + 2];
            v.w = sa_u[row * 33 + o * 4 + 3];
            *((uint4*)(h_out + (size_t)node0 * H) + tid) = v;
        }
    }
}

// block-per-graph max pool: binary search node range on sorted batch; no atomics
__global__ __launch_bounds__(256) void pool_max_kernel(
    const ushort* __restrict__ h, const int* __restrict__ batch,
    float* __restrict__ g)
{
    __shared__ float red[4][64];
    int b = blockIdx.x;
    int tid = threadIdx.x;
    int f = tid & 63, w = tid >> 6;
    int lo = 0, hi = NN;
    while (lo < hi) { int mid = (lo + hi) >> 1; if (batch[mid] < b) lo = mid + 1; else hi = mid; }
    int lo2 = lo, hi2 = NN;
    while (lo2 < hi2) { int mid = (lo2 + hi2) >> 1; if (batch[mid] < b + 1) lo2 = mid + 1; else hi2 = mid; }
    float m = -3.402823466e38f;
    for (int n = lo + w; n < lo2; n += 4) {
        ushort u = h[(size_t)n * H + f];
        m = fmaxf(m, __uint_as_float((uint)u << 16));
    }
    red[w][f] = m;
    __syncthreads();
    if (tid < 64) {
        float mm = fmaxf(fmaxf(red[0][f], red[1][f]), fmaxf(red[2][f], red[3][f]));
        g[b * H + f] = mm;
    }
}

__global__ __launch_bounds__(64) void mlp_kernel(
    const float* __restrict__ g,
    const float* __restrict__ fc1W, const float* __restrict__ fc1b,
    const float* __restrict__ fc2W, const float* __restrict__ fc2b,
    const float* __restrict__ fc3W, const float* __restrict__ fc3b,
    float* __restrict__ out)
{
    __shared__ float s0[64];
    __shared__ float s1[64];
    int b = blockIdx.x, j = threadIdx.x;
    s0[j] = g[b * H + j];
    __syncthreads();
    float acc = fc1b[j];
    for (int k = 0; k < 64; ++k) acc = fmaf(s0[k], fc1W[j * 64 + k], acc);
    s1[j] = fmaxf(acc, 0.f);
    __syncthreads();
    acc = fc2b[j];
    for (int k = 0; k < 64; ++k) acc = fmaf(s1[k], fc2W[j * 64 + k], acc);
    __syncthreads();
    s0[j] = fmaxf(acc, 0.f);
    __syncthreads();
    if (j < NC) {
        acc = fc3b[j];
        for (int k = 0; k < 64; ++k) acc = fmaf(s0[k], fc3W[j * 64 + k], acc);
        out[b * NC + j] = acc;
    }
}

// ---------------- launcher ----------------

extern "C" void kernel_launch(void* const* d_in, const int* in_sizes, int n_in,
                              void* d_out, int out_size, void* d_ws, size_t ws_size,
                              hipStream_t stream)
{
    const float* x         = (const float*)d_in[0];
    const int*   dst_ports = (const int*)d_in[1];
    const int*   tcp_flags = (const int*)d_in[2];
    const int*   edge_src_in = (const int*)d_in[3];          // row 0 of (2,E)
    const int*   edge_dst_in = edge_src_in + NE;             // row 1
    const int*   batch     = (const int*)d_in[4];
    const float* emb_port  = (const float*)d_in[5];
    const float* emb_flags = (const float*)d_in[6];
    const float* Wrel      = (const float*)d_in[7];
    const float* brel      = (const float*)d_in[8];
    const float* Wroot     = (const float*)d_in[9];
    const float* fc1W      = (const float*)d_in[10];
    const float* fc1b      = (const float*)d_in[11];
    const float* fc2W      = (const float*)d_in[12];
    const float* fc2b      = (const float*)d_in[13];
    const float* fc3W      = (const float*)d_in[14];
    const float* fc3b      = (const float*)d_in[15];
    float* out = (float*)d_out;

    // workspace carve-up (256B aligned)
    char* ws = (char*)d_ws;
    size_t off = 0;
    auto alloc = [&](size_t bytes) {
        void* p = ws + off;
        off += (bytes + 255) & ~(size_t)255;
        return p;
    };
    ushort* h0      = (ushort*)alloc((size_t)NN * H * 2);
    ushort* h1      = (ushort*)alloc((size_t)NN * H * 2);
    int*   cnt      = (int*)alloc((size_t)NN * 4);
    int*   row_start= (int*)alloc((size_t)(NN + 1) * 4);
    int*   cursor   = (int*)alloc((size_t)NN * 4);
    int*   edge_src = (int*)alloc((size_t)NE * 4);
    float* g        = (float*)alloc((size_t)NB * H * 4);
    int*   bsum     = (int*)alloc((size_t)64 * 4);

    // h0 = concat(...) in bf16; also zeroes cnt (before hist)
    embed_concat_kernel<<<(NN * 32 + 255) / 256, 256, 0, stream>>>(
        x, dst_ports, tcp_flags, emb_port, emb_flags, h0, cnt);

    // CSR build (by dst)
    hist_kernel<<<(NE + 255) / 256, 256, 0, stream>>>(edge_dst_in, cnt);
    scan1_kernel<<<(NN + 1023) / 1024, 1024, 0, stream>>>(cnt, row_start, bsum, cursor);
    scan2_kernel<<<1, 64, 0, stream>>>(bsum);
    scan3_kernel<<<(NN + 1023) / 1024 - 1, 1024, 0, stream>>>(row_start, bsum);
    scatter_edges_kernel<<<(NE + 255) / 256, 256, 0, stream>>>(
        edge_src_in, edge_dst_in, row_start, cursor, edge_src);

    // 3 fused GraphConv layers, ping-pong
    const int cgrid = (NN + TILE - 1) / TILE;
    conv_kernel<<<cgrid, 256, 0, stream>>>(
        h0, h1, row_start, edge_src, Wrel + 0 * H * H, brel + 0 * H, Wroot + 0 * H * H);
    conv_kernel<<<cgrid, 256, 0, stream>>>(
        h1, h0, row_start, edge_src, Wrel + 1 * H * H, brel + 1 * H, Wroot + 1 * H * H);
    conv_kernel<<<cgrid, 256, 0, stream>>>(
        h0, h1, row_start, edge_src, Wrel + 2 * H * H, brel + 2 * H, Wroot + 2 * H * H);

    // global max pool (final h is h1), block per graph, no atomics
    pool_max_kernel<<<NB, 256, 0, stream>>>(h1, batch, g);

    // MLP head
    mlp_kernel<<<NB, 64, 0, stream>>>(g, fc1W, fc1b, fc2W, fc2b, fc3W, fc3b, out);
}

// Round 7
// 406.857 us; speedup vs baseline: 1.2652x; 1.0886x over previous
//
#include <hip/hip_runtime.h>

#define NN 50000
#define NE 800000
#define NB 128
#define FIN 30
#define H 64
#define NC 10
#define L 3
#define TILE 32
#define CAP 1024   // staged edge offsets per tile (avg ~512, 22 sigma headroom)

typedef unsigned int uint;
typedef unsigned short ushort;

// f32 -> bf16 round-to-nearest-even (finite inputs)
__device__ __forceinline__ ushort f2bf(float x) {
    uint u = __float_as_uint(x);
    u += 0x7fffu + ((u >> 16) & 1u);
    return (ushort)(u >> 16);
}
__device__ __forceinline__ float bf_lo(uint v) { return __uint_as_float(v << 16); }
__device__ __forceinline__ float bf_hi(uint v) { return __uint_as_float(v & 0xffff0000u); }

// ---------------- kernels ----------------

// h0 = concat(x, emb_port[ports], emb_flags[flags]) in bf16; also zeroes cnt.
__global__ __launch_bounds__(256) void embed_concat_kernel(
    const float* __restrict__ x, const int* __restrict__ ports,
    const int* __restrict__ flags, const float* __restrict__ emb_port,
    const float* __restrict__ emb_flags, ushort* __restrict__ h,
    int* __restrict__ cnt)
{
    int tid = blockIdx.x * 256 + threadIdx.x;
    int n = tid >> 5, fp = tid & 31;
    if (n >= NN) return;
    if (fp == 0) cnt[n] = 0;
    int f0 = fp * 2;
    float v0, v1;
    if (f0 < FIN) {
        float2 xv = *(const float2*)(x + (size_t)n * FIN + f0);
        v0 = xv.x; v1 = xv.y;
    } else if (f0 < FIN + 32) {
        float2 pv = *(const float2*)(emb_port + (size_t)ports[n] * 32 + (f0 - FIN));
        v0 = pv.x; v1 = pv.y;
    } else {
        float2 fv = *(const float2*)(emb_flags + (size_t)flags[n] * 2);
        v0 = fv.x; v1 = fv.y;
    }
    uint o = (uint)f2bf(v0) | ((uint)f2bf(v1) << 16);
    ((uint*)h)[n * 32 + fp] = o;
}

__global__ __launch_bounds__(256) void hist_kernel(
    const int* __restrict__ dst, int* __restrict__ cnt)
{
    int e = blockIdx.x * 256 + threadIdx.x;
    if (e < NE) atomicAdd(&cnt[dst[e]], 1);
}

// ---- hierarchical scan; also zeroes cursor (used later by scatter) ----

__global__ __launch_bounds__(1024) void scan1_kernel(
    const int* __restrict__ cnt, int* __restrict__ row_start,
    int* __restrict__ bsum, int* __restrict__ cursor)
{
    __shared__ int wsum[16];
    int i = blockIdx.x * 1024 + threadIdx.x;
    int lane = threadIdx.x & 63;
    int wv = threadIdx.x >> 6;
    if (i < NN) cursor[i] = 0;
    int v = (i < NN) ? cnt[i] : 0;
    int s = v;
    for (int off = 1; off < 64; off <<= 1) {
        int t = __shfl_up(s, off);
        if (lane >= off) s += t;
    }
    if (lane == 63) wsum[wv] = s;
    __syncthreads();
    if (wv == 0) {
        int ws = (lane < 16) ? wsum[lane] : 0;
        for (int off = 1; off < 16; off <<= 1) {
            int t = __shfl_up(ws, off);
            if (lane >= off) ws += t;
        }
        if (lane < 16) wsum[lane] = ws;
    }
    __syncthreads();
    int base = (wv > 0) ? wsum[wv - 1] : 0;
    s += base;
    if (i < NN) row_start[i + 1] = s;
    if (threadIdx.x == 1023) bsum[blockIdx.x] = s;
    if (i == 0) row_start[0] = 0;
}

__global__ __launch_bounds__(64) void scan2_kernel(int* __restrict__ bsum)
{
    int lane = threadIdx.x;
    int v = (lane < 49) ? bsum[lane] : 0;
    for (int off = 1; off < 64; off <<= 1) {
        int t = __shfl_up(v, off);
        if (lane >= off) v += t;
    }
    if (lane < 49) bsum[lane] = v;
}

__global__ __launch_bounds__(1024) void scan3_kernel(
    int* __restrict__ row_start, const int* __restrict__ bsum)
{
    int b = blockIdx.x + 1;
    int i = b * 1024 + threadIdx.x;
    if (i < NN) row_start[i + 1] += bsum[b - 1];
}

// CSR bucket fill; stores BYTE offsets (src * 128). Index guard keeps rocprof
// counter-replay (re-runs without re-zeroed cursor) in bounds.
__global__ __launch_bounds__(256) void scatter_edges_kernel(
    const int* __restrict__ src, const int* __restrict__ dst,
    const int* __restrict__ row_start, int* __restrict__ cursor,
    int* __restrict__ edge_src)
{
    int e = blockIdx.x * 256 + threadIdx.x;
    if (e >= NE) return;
    int d = dst[e];
    int pos = atomicAdd(&cursor[d], 1);
    int idx = row_start[d] + pos;
    if (idx < NE) edge_src[idx] = src[e] << 7;
}

// fused GraphConv layer, bf16 h.
// Gather: lane = (row_local, oct) — each lane privately accumulates 8 features
// of one row over its full edge list (no cross-lane reduce, no per-row sync);
// 4-deep predicated unroll => ~32 independent gathers in flight per wave.
// Edge offsets pre-staged in LDS. Output restaged through LDS for coalesced
// full-line stores.
__global__ __launch_bounds__(256) void conv_kernel(
    const ushort* __restrict__ h_in, ushort* __restrict__ h_out,
    const int* __restrict__ row_start, const int* __restrict__ edge_src,
    const float* __restrict__ Wrel, const float* __restrict__ brel,
    const float* __restrict__ Wroot)
{
    __shared__ float sa[TILE * 65];   // aggregated neighbor sums (f32); reused as out-stage
    __shared__ float sh[TILE * 65];   // self rows (f32, from bf16)
    __shared__ int   se[CAP];         // staged edge byte-offsets for the tile
    __shared__ int   rs[TILE + 1];
    int node0 = blockIdx.x * TILE;
    int tid = threadIdx.x;

    if (tid < TILE + 1) {
        int idx = node0 + tid; if (idx > NN) idx = NN;
        rs[tid] = row_start[idx];
    }
    __syncthreads();
    int rs0  = rs[0];
    int ecnt = rs[TILE] - rs0;

    // stage edge offsets (coalesced)
    for (int t = tid; t < ecnt && t < CAP; t += 256) se[t] = edge_src[rs0 + t];

    // self staging: 256 threads x 16B (8 bf16 -> f32)
    {
        int r = tid >> 3, oct = tid & 7;
        uint4 v = make_uint4(0u, 0u, 0u, 0u);
        if (node0 + r < NN)
            v = *((const uint4*)(h_in + (size_t)node0 * H) + tid);
        float* d = &sh[r * 65 + oct * 8];
        d[0] = bf_lo(v.x); d[1] = bf_hi(v.x);
        d[2] = bf_lo(v.y); d[3] = bf_hi(v.y);
        d[4] = bf_lo(v.z); d[5] = bf_hi(v.z);
        d[6] = bf_lo(v.w); d[7] = bf_hi(v.w);
    }
    __syncthreads();

    // gather: lane owns (row rloc, feature-octet oct); private f32 accumulation
    {
        int rloc = tid >> 3;            // 0..31 (wave w covers rows w*8..w*8+7)
        int oct  = tid & 7;
        const char* hbo = (const char*)h_in + oct * 16;
        int eabs = rs[rloc];
        int deg  = rs[rloc + 1] - eabs;
        int eloc = eabs - rs0;
        float a[8] = {0.f,0.f,0.f,0.f,0.f,0.f,0.f,0.f};
        if (ecnt <= CAP) {
            for (int k = 0; k < deg; k += 4) {
                int o0 = se[eloc + k];
                bool g1 = k + 1 < deg, g2 = k + 2 < deg, g3 = k + 3 < deg;
                int o1 = g1 ? se[eloc + k + 1] : 0;
                int o2 = g2 ? se[eloc + k + 2] : 0;
                int o3 = g3 ? se[eloc + k + 3] : 0;
                uint4 v0 = *(const uint4*)(hbo + o0);
                uint4 v1 = make_uint4(0u,0u,0u,0u);
                uint4 v2 = make_uint4(0u,0u,0u,0u);
                uint4 v3 = make_uint4(0u,0u,0u,0u);
                if (g1) v1 = *(const uint4*)(hbo + o1);
                if (g2) v2 = *(const uint4*)(hbo + o2);
                if (g3) v3 = *(const uint4*)(hbo + o3);
                a[0] += (bf_lo(v0.x) + bf_lo(v1.x)) + (bf_lo(v2.x) + bf_lo(v3.x));
                a[1] += (bf_hi(v0.x) + bf_hi(v1.x)) + (bf_hi(v2.x) + bf_hi(v3.x));
                a[2] += (bf_lo(v0.y) + bf_lo(v1.y)) + (bf_lo(v2.y) + bf_lo(v3.y));
                a[3] += (bf_hi(v0.y) + bf_hi(v1.y)) + (bf_hi(v2.y) + bf_hi(v3.y));
                a[4] += (bf_lo(v0.z) + bf_lo(v1.z)) + (bf_lo(v2.z) + bf_lo(v3.z));
                a[5] += (bf_hi(v0.z) + bf_hi(v1.z)) + (bf_hi(v2.z) + bf_hi(v3.z));
                a[6] += (bf_lo(v0.w) + bf_lo(v1.w)) + (bf_lo(v2.w) + bf_lo(v3.w));
                a[7] += (bf_hi(v0.w) + bf_hi(v1.w)) + (bf_hi(v2.w) + bf_hi(v3.w));
            }
        } else {
            // statistically unreachable fallback (tile edge count > CAP)
            const int* ep = edge_src + eabs;
            for (int k = 0; k < deg; ++k) {
                uint4 v = *(const uint4*)(hbo + ep[k]);
                a[0] += bf_lo(v.x); a[1] += bf_hi(v.x);
                a[2] += bf_lo(v.y); a[3] += bf_hi(v.y);
                a[4] += bf_lo(v.z); a[5] += bf_hi(v.z);
                a[6] += bf_lo(v.w); a[7] += bf_hi(v.w);
            }
        }
        float* d = &sa[rloc * 65 + oct * 8];
#pragma unroll
        for (int e = 0; e < 8; ++e) d[e] = a[e];
    }
    __syncthreads();

    // linear phase: thread = (node r2, 8-feature chunk c)
    int r2 = tid & 31;
    int c  = tid >> 5;
    int jt = c * 8;
    float acc[8];
#pragma unroll
    for (int j = 0; j < 8; ++j) acc[j] = brel[jt + j];
#pragma unroll 4
    for (int k = 0; k < 64; ++k) {
        float av = sa[r2 * 65 + k];
        float hv = sh[r2 * 65 + k];
#pragma unroll
        for (int j = 0; j < 8; ++j) {
            acc[j] = fmaf(av, Wrel[(jt + j) * 64 + k],
                     fmaf(hv, Wroot[(jt + j) * 64 + k], acc[j]));
        }
    }
    __syncthreads();   // all sa/sh reads done; safe to reuse sa as output stage

    // pack relu(acc) as bf16 pairs into padded LDS stage: [32 rows][33 words]
    {
        uint* sa_u = (uint*)sa;
#pragma unroll
        for (int q = 0; q < 4; ++q) {
            float lo = fmaxf(acc[2 * q],     0.f);
            float hi = fmaxf(acc[2 * q + 1], 0.f);
            sa_u[r2 * 33 + c * 4 + q] = (uint)f2bf(lo) | ((uint)f2bf(hi) << 16);
        }
    }
    __syncthreads();

    // coalesced store pass: thread tid writes 16B at byte offset tid*16 of the tile
    {
        const uint* sa_u = (const uint*)sa;
        int row = tid >> 3;
        int o   = tid & 7;
        if (node0 + row < NN) {
            uint4 v;
            v.x = sa_u[row * 33 + o * 4 + 0];
            v.y = sa_u[row * 33 + o * 4 + 1];
            v.z = sa_u[row * 33 + o * 4 + 2];
            v.w = sa_u[row * 33 + o * 4 + 3];
            *((uint4*)(h_out + (size_t)node0 * H) + tid) = v;
        }
    }
}

// fused max-pool + MLP head: one block per graph
__global__ __launch_bounds__(256) void pool_mlp_kernel(
    const ushort* __restrict__ h, const int* __restrict__ batch,
    const float* __restrict__ fc1W, const float* __restrict__ fc1b,
    const float* __restrict__ fc2W, const float* __restrict__ fc2b,
    const float* __restrict__ fc3W, const float* __restrict__ fc3b,
    float* __restrict__ out)
{
    __shared__ float red[4][64];
    __shared__ float s0[64];
    __shared__ float s1[64];
    __shared__ float s2[64];
    int b = blockIdx.x;
    int tid = threadIdx.x;
    int f = tid & 63, w = tid >> 6;
    int lo = 0, hi = NN;
    while (lo < hi) { int mid = (lo + hi) >> 1; if (batch[mid] < b) lo = mid + 1; else hi = mid; }
    int lo2 = lo, hi2 = NN;
    while (lo2 < hi2) { int mid = (lo2 + hi2) >> 1; if (batch[mid] < b + 1) lo2 = mid + 1; else hi2 = mid; }
    float m = -3.402823466e38f;
    for (int n = lo + w; n < lo2; n += 4) {
        ushort u = h[(size_t)n * H + f];
        m = fmaxf(m, __uint_as_float((uint)u << 16));
    }
    red[w][f] = m;
    __syncthreads();
    int j = tid;
    if (tid < 64)
        s0[j] = fmaxf(fmaxf(red[0][j], red[1][j]), fmaxf(red[2][j], red[3][j]));
    __syncthreads();
    float acc = 0.f;
    if (tid < 64) {
        acc = fc1b[j];
        for (int k = 0; k < 64; ++k) acc = fmaf(s0[k], fc1W[j * 64 + k], acc);
    }
    __syncthreads();
    if (tid < 64) s1[j] = fmaxf(acc, 0.f);
    __syncthreads();
    if (tid < 64) {
        acc = fc2b[j];
        for (int k = 0; k < 64; ++k) acc = fmaf(s1[k], fc2W[j * 64 + k], acc);
    }
    __syncthreads();
    if (tid < 64) s2[j] = fmaxf(acc, 0.f);
    __syncthreads();
    if (tid < NC) {
        acc = fc3b[j];
        for (int k = 0; k < 64; ++k) acc = fmaf(s2[k], fc3W[j * 64 + k], acc);
        out[b * NC + j] = acc;
    }
}

// ---------------- launcher ----------------

extern "C" void kernel_launch(void* const* d_in, const int* in_sizes, int n_in,
                              void* d_out, int out_size, void* d_ws, size_t ws_size,
                              hipStream_t stream)
{
    const float* x         = (const float*)d_in[0];
    const int*   dst_ports = (const int*)d_in[1];
    const int*   tcp_flags = (const int*)d_in[2];
    const int*   edge_src_in = (const int*)d_in[3];          // row 0 of (2,E)
    const int*   edge_dst_in = edge_src_in + NE;             // row 1
    const int*   batch     = (const int*)d_in[4];
    const float* emb_port  = (const float*)d_in[5];
    const float* emb_flags = (const float*)d_in[6];
    const float* Wrel      = (const float*)d_in[7];
    const float* brel      = (const float*)d_in[8];
    const float* Wroot     = (const float*)d_in[9];
    const float* fc1W      = (const float*)d_in[10];
    const float* fc1b      = (const float*)d_in[11];
    const float* fc2W      = (const float*)d_in[12];
    const float* fc2b      = (const float*)d_in[13];
    const float* fc3W      = (const float*)d_in[14];
    const float* fc3b      = (const float*)d_in[15];
    float* out = (float*)d_out;

    // workspace carve-up (256B aligned)
    char* ws = (char*)d_ws;
    size_t off = 0;
    auto alloc = [&](size_t bytes) {
        void* p = ws + off;
        off += (bytes + 255) & ~(size_t)255;
        return p;
    };
    ushort* h0      = (ushort*)alloc((size_t)NN * H * 2);
    ushort* h1      = (ushort*)alloc((size_t)NN * H * 2);
    int*   cnt      = (int*)alloc((size_t)NN * 4);
    int*   row_start= (int*)alloc((size_t)(NN + 1) * 4);
    int*   cursor   = (int*)alloc((size_t)NN * 4);
    int*   edge_src = (int*)alloc((size_t)NE * 4);
    int*   bsum     = (int*)alloc((size_t)64 * 4);

    // h0 = concat(...) in bf16; also zeroes cnt (before hist)
    embed_concat_kernel<<<(NN * 32 + 255) / 256, 256, 0, stream>>>(
        x, dst_ports, tcp_flags, emb_port, emb_flags, h0, cnt);

    // CSR build (by dst)
    hist_kernel<<<(NE + 255) / 256, 256, 0, stream>>>(edge_dst_in, cnt);
    scan1_kernel<<<(NN + 1023) / 1024, 1024, 0, stream>>>(cnt, row_start, bsum, cursor);
    scan2_kernel<<<1, 64, 0, stream>>>(bsum);
    scan3_kernel<<<(NN + 1023) / 1024 - 1, 1024, 0, stream>>>(row_start, bsum);
    scatter_edges_kernel<<<(NE + 255) / 256, 256, 0, stream>>>(
        edge_src_in, edge_dst_in, row_start, cursor, edge_src);

    // 3 fused GraphConv layers, ping-pong
    const int cgrid = (NN + TILE - 1) / TILE;
    conv_kernel<<<cgrid, 256, 0, stream>>>(
        h0, h1, row_start, edge_src, Wrel + 0 * H * H, brel + 0 * H, Wroot + 0 * H * H);
    conv_kernel<<<cgrid, 256, 0, stream>>>(
        h1, h0, row_start, edge_src, Wrel + 1 * H * H, brel + 1 * H, Wroot + 1 * H * H);
    conv_kernel<<<cgrid, 256, 0, stream>>>(
        h0, h1, row_start, edge_src, Wrel + 2 * H * H, brel + 2 * H, Wroot + 2 * H * H);

    // fused global max pool + MLP head (final h is h1)
    pool_mlp_kernel<<<NB, 256, 0, stream>>>(
        h1, batch, fc1W, fc1b, fc2W, fc2b, fc3W, fc3b, out);
}

// Round 8
// 317.982 us; speedup vs baseline: 1.6189x; 1.2795x over previous
//
#include <hip/hip_runtime.h>

#define NN 50000
#define NE 800000
#define NB 128
#define FIN 30
#define H 64
#define NC 10
#define L 3

typedef unsigned int uint;
typedef unsigned short ushort;

// f32 -> bf16 round-to-nearest-even (finite inputs)
__device__ __forceinline__ ushort f2bf(float x) {
    uint u = __float_as_uint(x);
    u += 0x7fffu + ((u >> 16) & 1u);
    return (ushort)(u >> 16);
}
__device__ __forceinline__ float bf_lo(uint v) { return __uint_as_float(v << 16); }
__device__ __forceinline__ float bf_hi(uint v) { return __uint_as_float(v & 0xffff0000u); }

// ---------------- kernels ----------------

// h0 = concat(x, emb_port[ports], emb_flags[flags]) in bf16; also zeroes cnt.
__global__ __launch_bounds__(256) void embed_concat_kernel(
    const float* __restrict__ x, const int* __restrict__ ports,
    const int* __restrict__ flags, const float* __restrict__ emb_port,
    const float* __restrict__ emb_flags, ushort* __restrict__ h,
    int* __restrict__ cnt)
{
    int tid = blockIdx.x * 256 + threadIdx.x;
    int n = tid >> 5, fp = tid & 31;
    if (n >= NN) return;
    if (fp == 0) cnt[n] = 0;
    int f0 = fp * 2;
    float v0, v1;
    if (f0 < FIN) {
        float2 xv = *(const float2*)(x + (size_t)n * FIN + f0);
        v0 = xv.x; v1 = xv.y;
    } else if (f0 < FIN + 32) {
        float2 pv = *(const float2*)(emb_port + (size_t)ports[n] * 32 + (f0 - FIN));
        v0 = pv.x; v1 = pv.y;
    } else {
        float2 fv = *(const float2*)(emb_flags + (size_t)flags[n] * 2);
        v0 = fv.x; v1 = fv.y;
    }
    uint o = (uint)f2bf(v0) | ((uint)f2bf(v1) << 16);
    ((uint*)h)[n * 32 + fp] = o;
}

// transpose weights: Wt[l][mat][k][j] = W[l][j][k]  (f32, 3*2*64*64)
__global__ __launch_bounds__(256) void prep_weights_kernel(
    const float* __restrict__ Wrel, const float* __restrict__ Wroot,
    float* __restrict__ Wt)
{
    int t = blockIdx.x * 256 + threadIdx.x;
    if (t >= L * 2 * H * H) return;
    int l = t / (2 * H * H), rem = t % (2 * H * H);
    int mat = rem / (H * H), kj = rem % (H * H);
    int k = kj >> 6, j = kj & 63;
    const float* W = mat ? Wroot : Wrel;
    Wt[t] = W[l * H * H + j * H + k];
}

__global__ __launch_bounds__(256) void hist_kernel(
    const int* __restrict__ dst, int* __restrict__ cnt)
{
    int e = blockIdx.x * 256 + threadIdx.x;
    if (e < NE) atomicAdd(&cnt[dst[e]], 1);
}

// ---- hierarchical scan; also zeroes cursor (used later by scatter) ----

__global__ __launch_bounds__(1024) void scan1_kernel(
    const int* __restrict__ cnt, int* __restrict__ row_start,
    int* __restrict__ bsum, int* __restrict__ cursor)
{
    __shared__ int wsum[16];
    int i = blockIdx.x * 1024 + threadIdx.x;
    int lane = threadIdx.x & 63;
    int wv = threadIdx.x >> 6;
    if (i < NN) cursor[i] = 0;
    int v = (i < NN) ? cnt[i] : 0;
    int s = v;
    for (int off = 1; off < 64; off <<= 1) {
        int t = __shfl_up(s, off);
        if (lane >= off) s += t;
    }
    if (lane == 63) wsum[wv] = s;
    __syncthreads();
    if (wv == 0) {
        int ws = (lane < 16) ? wsum[lane] : 0;
        for (int off = 1; off < 16; off <<= 1) {
            int t = __shfl_up(ws, off);
            if (lane >= off) ws += t;
        }
        if (lane < 16) wsum[lane] = ws;
    }
    __syncthreads();
    int base = (wv > 0) ? wsum[wv - 1] : 0;
    s += base;
    if (i < NN) row_start[i + 1] = s;
    if (threadIdx.x == 1023) bsum[blockIdx.x] = s;
    if (i == 0) row_start[0] = 0;
}

__global__ __launch_bounds__(64) void scan2_kernel(int* __restrict__ bsum)
{
    int lane = threadIdx.x;
    int v = (lane < 49) ? bsum[lane] : 0;
    for (int off = 1; off < 64; off <<= 1) {
        int t = __shfl_up(v, off);
        if (lane >= off) v += t;
    }
    if (lane < 49) bsum[lane] = v;
}

__global__ __launch_bounds__(1024) void scan3_kernel(
    int* __restrict__ row_start, const int* __restrict__ bsum)
{
    int b = blockIdx.x + 1;
    int i = b * 1024 + threadIdx.x;
    if (i < NN) row_start[i + 1] += bsum[b - 1];
}

// CSR bucket fill; stores BYTE offsets (src * 128). Index guard keeps rocprof
// counter-replay (re-runs without re-zeroed cursor) in bounds.
__global__ __launch_bounds__(256) void scatter_edges_kernel(
    const int* __restrict__ src, const int* __restrict__ dst,
    const int* __restrict__ row_start, int* __restrict__ cursor,
    int* __restrict__ edge_src)
{
    int e = blockIdx.x * 256 + threadIdx.x;
    if (e >= NE) return;
    int d = dst[e];
    int pos = atomicAdd(&cursor[d], 1);
    int idx = row_start[d] + pos;
    if (idx < NE) edge_src[idx] = src[e] << 7;
}

// dense per-node GEMMs: z0 = h@Wrel^T (bf16), z1 = h@Wroot^T + brel (bf16).
// 64 rows/block, 4 waves; wave = 16-output chunk (wave-uniform -> scalar
// weight loads from transposed Wt[k][j]); h rows staged in LDS as f32.
__global__ __launch_bounds__(256) void gemm_kernel(
    const ushort* __restrict__ h_in, const float* __restrict__ WtA,
    const float* __restrict__ WtB, const float* __restrict__ brel,
    ushort* __restrict__ z0, ushort* __restrict__ z1)
{
    __shared__ float sh[64 * 65];   // staged input rows (f32)
    __shared__ float so[64 * 65];   // output restage
    int node0 = blockIdx.x * 64;
    int tid = threadIdx.x;

    // stage h rows: 512 uint4 tasks (64 rows x 8 octs)
    for (int t = tid; t < 512; t += 256) {
        int r = t >> 3, oct = t & 7;
        uint4 v = make_uint4(0u, 0u, 0u, 0u);
        if (node0 + r < NN)
            v = *((const uint4*)(h_in + (size_t)node0 * H) + t);
        float* d = &sh[r * 65 + oct * 8];
        d[0] = bf_lo(v.x); d[1] = bf_hi(v.x);
        d[2] = bf_lo(v.y); d[3] = bf_hi(v.y);
        d[4] = bf_lo(v.z); d[5] = bf_hi(v.z);
        d[6] = bf_lo(v.w); d[7] = bf_hi(v.w);
    }
    __syncthreads();

    int r  = tid & 63;
    int jt = __builtin_amdgcn_readfirstlane((tid >> 6) * 16);  // wave-uniform
    float acc0[16], acc1[16];
#pragma unroll
    for (int j = 0; j < 16; ++j) { acc0[j] = 0.f; acc1[j] = brel[jt + j]; }
    for (int k = 0; k < 64; ++k) {
        float hv = sh[r * 65 + k];
        const float* wa = WtA + k * 64 + jt;
        const float* wb = WtB + k * 64 + jt;
#pragma unroll
        for (int j = 0; j < 16; ++j) {
            acc0[j] = fmaf(hv, wa[j], acc0[j]);
            acc1[j] = fmaf(hv, wb[j], acc1[j]);
        }
    }

    // z0: restage -> coalesced bf16 store
    __syncthreads();
#pragma unroll
    for (int j = 0; j < 16; ++j) so[r * 65 + jt + j] = acc0[j];
    __syncthreads();
    for (int t = tid; t < 512; t += 256) {
        int rr = t >> 3, oct = t & 7;
        if (node0 + rr < NN) {
            const float* s = &so[rr * 65 + oct * 8];
            uint4 v;
            v.x = (uint)f2bf(s[0]) | ((uint)f2bf(s[1]) << 16);
            v.y = (uint)f2bf(s[2]) | ((uint)f2bf(s[3]) << 16);
            v.z = (uint)f2bf(s[4]) | ((uint)f2bf(s[5]) << 16);
            v.w = (uint)f2bf(s[6]) | ((uint)f2bf(s[7]) << 16);
            *((uint4*)(z0 + (size_t)node0 * H) + t) = v;
        }
    }

    // z1: restage -> coalesced bf16 store
    __syncthreads();
#pragma unroll
    for (int j = 0; j < 16; ++j) so[r * 65 + jt + j] = acc1[j];
    __syncthreads();
    for (int t = tid; t < 512; t += 256) {
        int rr = t >> 3, oct = t & 7;
        if (node0 + rr < NN) {
            const float* s = &so[rr * 65 + oct * 8];
            uint4 v;
            v.x = (uint)f2bf(s[0]) | ((uint)f2bf(s[1]) << 16);
            v.y = (uint)f2bf(s[2]) | ((uint)f2bf(s[3]) << 16);
            v.z = (uint)f2bf(s[4]) | ((uint)f2bf(s[5]) << 16);
            v.w = (uint)f2bf(s[6]) | ((uint)f2bf(s[7]) << 16);
            *((uint4*)(z1 + (size_t)node0 * H) + t) = v;
        }
    }
}

// pure gather: h' = relu( sum_{j->n} z0[j] + z1[n] ).
// No LDS, no barriers: thread = (node n, oct); all waves independent and
// fully resident (6252 waves < 8192 slots) -> max memory-level parallelism.
__global__ __launch_bounds__(256) void gather_relu_kernel(
    const ushort* __restrict__ z0, const ushort* __restrict__ z1,
    const int* __restrict__ row_start, const int* __restrict__ edge_src,
    ushort* __restrict__ h_out)
{
    int tid = blockIdx.x * 256 + threadIdx.x;
    int n = tid >> 3, oct = tid & 7;
    if (n >= NN) return;
    int p0 = row_start[n], p1 = row_start[n + 1];
    const char* zb = (const char*)z0 + oct * 16;
    float a[8] = {0.f,0.f,0.f,0.f,0.f,0.f,0.f,0.f};
    for (int p = p0; p < p1; p += 4) {
        int o0 = edge_src[p];
        bool g1 = (p + 1) < p1, g2 = (p + 2) < p1, g3 = (p + 3) < p1;
        int o1 = g1 ? edge_src[p + 1] : 0;
        int o2 = g2 ? edge_src[p + 2] : 0;
        int o3 = g3 ? edge_src[p + 3] : 0;
        uint4 v0 = *(const uint4*)(zb + o0);
        uint4 v1 = make_uint4(0u,0u,0u,0u);
        uint4 v2 = make_uint4(0u,0u,0u,0u);
        uint4 v3 = make_uint4(0u,0u,0u,0u);
        if (g1) v1 = *(const uint4*)(zb + o1);
        if (g2) v2 = *(const uint4*)(zb + o2);
        if (g3) v3 = *(const uint4*)(zb + o3);
        a[0] += (bf_lo(v0.x) + bf_lo(v1.x)) + (bf_lo(v2.x) + bf_lo(v3.x));
        a[1] += (bf_hi(v0.x) + bf_hi(v1.x)) + (bf_hi(v2.x) + bf_hi(v3.x));
        a[2] += (bf_lo(v0.y) + bf_lo(v1.y)) + (bf_lo(v2.y) + bf_lo(v3.y));
        a[3] += (bf_hi(v0.y) + bf_hi(v1.y)) + (bf_hi(v2.y) + bf_hi(v3.y));
        a[4] += (bf_lo(v0.z) + bf_lo(v1.z)) + (bf_lo(v2.z) + bf_lo(v3.z));
        a[5] += (bf_hi(v0.z) + bf_hi(v1.z)) + (bf_hi(v2.z) + bf_hi(v3.z));
        a[6] += (bf_lo(v0.w) + bf_lo(v1.w)) + (bf_lo(v2.w) + bf_lo(v3.w));
        a[7] += (bf_hi(v0.w) + bf_hi(v1.w)) + (bf_hi(v2.w) + bf_hi(v3.w));
    }
    uint4 sv = *(const uint4*)((const char*)z1 + (size_t)n * 128 + oct * 16);
    a[0] += bf_lo(sv.x); a[1] += bf_hi(sv.x);
    a[2] += bf_lo(sv.y); a[3] += bf_hi(sv.y);
    a[4] += bf_lo(sv.z); a[5] += bf_hi(sv.z);
    a[6] += bf_lo(sv.w); a[7] += bf_hi(sv.w);
    uint4 o;
    o.x = (uint)f2bf(fmaxf(a[0], 0.f)) | ((uint)f2bf(fmaxf(a[1], 0.f)) << 16);
    o.y = (uint)f2bf(fmaxf(a[2], 0.f)) | ((uint)f2bf(fmaxf(a[3], 0.f)) << 16);
    o.z = (uint)f2bf(fmaxf(a[4], 0.f)) | ((uint)f2bf(fmaxf(a[5], 0.f)) << 16);
    o.w = (uint)f2bf(fmaxf(a[6], 0.f)) | ((uint)f2bf(fmaxf(a[7], 0.f)) << 16);
    *((uint4*)h_out + tid) = o;   // tid*16 == n*128 + oct*16 : fully contiguous
}

// fused max-pool + MLP head: one block per graph
__global__ __launch_bounds__(256) void pool_mlp_kernel(
    const ushort* __restrict__ h, const int* __restrict__ batch,
    const float* __restrict__ fc1W, const float* __restrict__ fc1b,
    const float* __restrict__ fc2W, const float* __restrict__ fc2b,
    const float* __restrict__ fc3W, const float* __restrict__ fc3b,
    float* __restrict__ out)
{
    __shared__ float red[4][64];
    __shared__ float s0[64];
    __shared__ float s1[64];
    __shared__ float s2[64];
    int b = blockIdx.x;
    int tid = threadIdx.x;
    int f = tid & 63, w = tid >> 6;
    int lo = 0, hi = NN;
    while (lo < hi) { int mid = (lo + hi) >> 1; if (batch[mid] < b) lo = mid + 1; else hi = mid; }
    int lo2 = lo, hi2 = NN;
    while (lo2 < hi2) { int mid = (lo2 + hi2) >> 1; if (batch[mid] < b + 1) lo2 = mid + 1; else hi2 = mid; }
    float m = -3.402823466e38f;
    for (int n = lo + w; n < lo2; n += 4) {
        ushort u = h[(size_t)n * H + f];
        m = fmaxf(m, __uint_as_float((uint)u << 16));
    }
    red[w][f] = m;
    __syncthreads();
    int j = tid;
    if (tid < 64)
        s0[j] = fmaxf(fmaxf(red[0][j], red[1][j]), fmaxf(red[2][j], red[3][j]));
    __syncthreads();
    float acc = 0.f;
    if (tid < 64) {
        acc = fc1b[j];
        for (int k = 0; k < 64; ++k) acc = fmaf(s0[k], fc1W[j * 64 + k], acc);
    }
    __syncthreads();
    if (tid < 64) s1[j] = fmaxf(acc, 0.f);
    __syncthreads();
    if (tid < 64) {
        acc = fc2b[j];
        for (int k = 0; k < 64; ++k) acc = fmaf(s1[k], fc2W[j * 64 + k], acc);
    }
    __syncthreads();
    if (tid < 64) s2[j] = fmaxf(acc, 0.f);
    __syncthreads();
    if (tid < NC) {
        acc = fc3b[j];
        for (int k = 0; k < 64; ++k) acc = fmaf(s2[k], fc3W[j * 64 + k], acc);
        out[b * NC + j] = acc;
    }
}

// ---------------- launcher ----------------

extern "C" void kernel_launch(void* const* d_in, const int* in_sizes, int n_in,
                              void* d_out, int out_size, void* d_ws, size_t ws_size,
                              hipStream_t stream)
{
    const float* x         = (const float*)d_in[0];
    const int*   dst_ports = (const int*)d_in[1];
    const int*   tcp_flags = (const int*)d_in[2];
    const int*   edge_src_in = (const int*)d_in[3];          // row 0 of (2,E)
    const int*   edge_dst_in = edge_src_in + NE;             // row 1
    const int*   batch     = (const int*)d_in[4];
    const float* emb_port  = (const float*)d_in[5];
    const float* emb_flags = (const float*)d_in[6];
    const float* Wrel      = (const float*)d_in[7];
    const float* brel      = (const float*)d_in[8];
    const float* Wroot     = (const float*)d_in[9];
    const float* fc1W      = (const float*)d_in[10];
    const float* fc1b      = (const float*)d_in[11];
    const float* fc2W      = (const float*)d_in[12];
    const float* fc2b      = (const float*)d_in[13];
    const float* fc3W      = (const float*)d_in[14];
    const float* fc3b      = (const float*)d_in[15];
    float* out = (float*)d_out;

    // workspace carve-up (256B aligned)
    char* ws = (char*)d_ws;
    size_t off = 0;
    auto alloc = [&](size_t bytes) {
        void* p = ws + off;
        off += (bytes + 255) & ~(size_t)255;
        return p;
    };
    ushort* h0      = (ushort*)alloc((size_t)NN * H * 2);
    ushort* h1      = (ushort*)alloc((size_t)NN * H * 2);
    ushort* z0      = (ushort*)alloc((size_t)NN * H * 2);
    ushort* z1      = (ushort*)alloc((size_t)NN * H * 2);
    int*   cnt      = (int*)alloc((size_t)NN * 4);
    int*   row_start= (int*)alloc((size_t)(NN + 1) * 4);
    int*   cursor   = (int*)alloc((size_t)NN * 4);
    int*   edge_src = (int*)alloc((size_t)NE * 4);
    int*   bsum     = (int*)alloc((size_t)64 * 4);
    float* Wt       = (float*)alloc((size_t)L * 2 * H * H * 4);

    // h0 = concat(...) in bf16; also zeroes cnt (before hist)
    embed_concat_kernel<<<(NN * 32 + 255) / 256, 256, 0, stream>>>(
        x, dst_ports, tcp_flags, emb_port, emb_flags, h0, cnt);

    // weight transpose (tiny)
    prep_weights_kernel<<<(L * 2 * H * H + 255) / 256, 256, 0, stream>>>(Wrel, Wroot, Wt);

    // CSR build (by dst)
    hist_kernel<<<(NE + 255) / 256, 256, 0, stream>>>(edge_dst_in, cnt);
    scan1_kernel<<<(NN + 1023) / 1024, 1024, 0, stream>>>(cnt, row_start, bsum, cursor);
    scan2_kernel<<<1, 64, 0, stream>>>(bsum);
    scan3_kernel<<<(NN + 1023) / 1024 - 1, 1024, 0, stream>>>(row_start, bsum);
    scatter_edges_kernel<<<(NE + 255) / 256, 256, 0, stream>>>(
        edge_src_in, edge_dst_in, row_start, cursor, edge_src);

    // 3 layers: dense GEMMs then pure gather; ping-pong h0<->h1
    const int ggrid = (NN + 63) / 64;
    const int agrid = (NN * 8 + 255) / 256;
    ushort* hin = h0; ushort* hout = h1;
    for (int l = 0; l < L; ++l) {
        gemm_kernel<<<ggrid, 256, 0, stream>>>(
            hin, Wt + (size_t)l * 2 * H * H, Wt + (size_t)l * 2 * H * H + H * H,
            brel + (size_t)l * H, z0, z1);
        gather_relu_kernel<<<agrid, 256, 0, stream>>>(z0, z1, row_start, edge_src, hout);
        ushort* tmp = hin; hin = hout; hout = tmp;
    }

    // fused global max pool + MLP head (final h is hin after swap)
    pool_mlp_kernel<<<NB, 256, 0, stream>>>(
        hin, batch, fc1W, fc1b, fc2W, fc2b, fc3W, fc3b, out);
}